// Round 6
// baseline (5265.746 us; speedup 1.0000x reference)
//
#include <hip/hip_runtime.h>
#include <math.h>

#define DIM 128
#define N_ENT 100000
#define N_REL 500
#define N_EDGE 3200000
#define LN_EPS 1e-6f
#define ALPHA 0.2f
#define RPB 64   // rows per block in row-kernels (4 waves x 4 rows x 4 passes)

// ---------- helpers ----------

__device__ __forceinline__ float wred(float v) {
#pragma unroll
  for (int o = 32; o > 0; o >>= 1) v += __shfl_xor(v, o, 64);
  return v;
}

// legacy one-row wave GEMV (used only for the tiny R=500 kernels)
__device__ __forceinline__ float2 wave_gemv(float q0, float q1, const float* __restrict__ Wl, int lane) {
  float ax = 0.f, ay = 0.f;
#pragma unroll
  for (int kk = 0; kk < 64; ++kk) {
    float qa = __shfl(q0, kk, 64);
    float qb = __shfl(q1, kk, 64);
    float2 w0 = *(const float2*)&Wl[(2 * kk) * DIM + 2 * lane];
    float2 w1 = *(const float2*)&Wl[(2 * kk + 1) * DIM + 2 * lane];
    ax = fmaf(qa, w0.x, ax); ay = fmaf(qa, w0.y, ay);
    ax = fmaf(qb, w1.x, ax); ay = fmaf(qb, w1.y, ay);
  }
  return make_float2(ax, ay);
}

__device__ __forceinline__ void stageW(float* Wl, const float* __restrict__ W) {
  for (int i = threadIdx.x; i < DIM * DIM / 4; i += blockDim.x)
    ((float4*)Wl)[i] = ((const float4*)W)[i];
  __syncthreads();
}

__device__ __forceinline__ void wave_ln(float x0, float x1, float& d0s, float& d1s) {
  float m = wred(x0 + x1) * (1.f / DIM);
  float d0 = x0 - m, d1 = x1 - m;
  float var = wred(d0 * d0 + d1 * d1) * (1.f / DIM);
  float rs = rsqrtf(var + LN_EPS);
  d0s = d0 * rs; d1s = d1 * rs;
}

// 4-rows-per-wave GEMV from per-wave q tile (broadcast reads) x W in LDS.
// acc[j] = q_row_j @ W, lane owns cols (2*lane, 2*lane+1).
__device__ __forceinline__ void quad_gemv(const float* __restrict__ Qw /*4x DIM*/,
                                          const float* __restrict__ Wl,
                                          int lane, float2 acc[4]) {
#pragma unroll
  for (int j = 0; j < 4; ++j) acc[j] = make_float2(0.f, 0.f);
#pragma unroll
  for (int k = 0; k < DIM; k += 4) {
    float4 qa = *(const float4*)&Qw[0 * DIM + k];
    float4 qb = *(const float4*)&Qw[1 * DIM + k];
    float4 qc = *(const float4*)&Qw[2 * DIM + k];
    float4 qd = *(const float4*)&Qw[3 * DIM + k];
    float2 w0 = *(const float2*)&Wl[(k + 0) * DIM + 2 * lane];
    float2 w1 = *(const float2*)&Wl[(k + 1) * DIM + 2 * lane];
    float2 w2 = *(const float2*)&Wl[(k + 2) * DIM + 2 * lane];
    float2 w3 = *(const float2*)&Wl[(k + 3) * DIM + 2 * lane];
    acc[0].x = fmaf(qa.x, w0.x, acc[0].x); acc[0].y = fmaf(qa.x, w0.y, acc[0].y);
    acc[0].x = fmaf(qa.y, w1.x, acc[0].x); acc[0].y = fmaf(qa.y, w1.y, acc[0].y);
    acc[0].x = fmaf(qa.z, w2.x, acc[0].x); acc[0].y = fmaf(qa.z, w2.y, acc[0].y);
    acc[0].x = fmaf(qa.w, w3.x, acc[0].x); acc[0].y = fmaf(qa.w, w3.y, acc[0].y);
    acc[1].x = fmaf(qb.x, w0.x, acc[1].x); acc[1].y = fmaf(qb.x, w0.y, acc[1].y);
    acc[1].x = fmaf(qb.y, w1.x, acc[1].x); acc[1].y = fmaf(qb.y, w1.y, acc[1].y);
    acc[1].x = fmaf(qb.z, w2.x, acc[1].x); acc[1].y = fmaf(qb.z, w2.y, acc[1].y);
    acc[1].x = fmaf(qb.w, w3.x, acc[1].x); acc[1].y = fmaf(qb.w, w3.y, acc[1].y);
    acc[2].x = fmaf(qc.x, w0.x, acc[2].x); acc[2].y = fmaf(qc.x, w0.y, acc[2].y);
    acc[2].x = fmaf(qc.y, w1.x, acc[2].x); acc[2].y = fmaf(qc.y, w1.y, acc[2].y);
    acc[2].x = fmaf(qc.z, w2.x, acc[2].x); acc[2].y = fmaf(qc.z, w2.y, acc[2].y);
    acc[2].x = fmaf(qc.w, w3.x, acc[2].x); acc[2].y = fmaf(qc.w, w3.y, acc[2].y);
    acc[3].x = fmaf(qd.x, w0.x, acc[3].x); acc[3].y = fmaf(qd.x, w0.y, acc[3].y);
    acc[3].x = fmaf(qd.y, w1.x, acc[3].x); acc[3].y = fmaf(qd.y, w1.y, acc[3].y);
    acc[3].x = fmaf(qd.z, w2.x, acc[3].x); acc[3].y = fmaf(qd.z, w2.y, acc[3].y);
    acc[3].x = fmaf(qd.w, w3.x, acc[3].x); acc[3].y = fmaf(qd.w, w3.y, acc[3].y);
  }
}

// ---------- precompute: column-structure sums for local-attn sum1/sum2 ----------
// sum(q@W1+b1, axis=1) == q . rowsum_j(W1[k][j]) + sum(b1)
__global__ void k_colsum(const float* __restrict__ W1, const float* __restrict__ b1,
                         const float* __restrict__ W2, const float* __restrict__ b2,
                         float* __restrict__ w1s, float* __restrict__ w2s, float* __restrict__ cst) {
  int t = threadIdx.x;  // 128 threads
  float s1 = 0.f, s2 = 0.f;
  for (int j = 0; j < DIM; ++j) { s1 += W1[t * DIM + j]; s2 += W2[t * DIM + j]; }
  w1s[t] = s1; w2s[t] = s2;
  if (t == 0) {
    float a = 0.f, c = 0.f;
    for (int j = 0; j < DIM; ++j) { a += b1[j]; c += b2[j]; }
    cst[0] = a; cst[1] = c;
  }
}

// ---------- K1: local-attn row pass: LN -> value GEMV, sum1/sum2 dots ----------
__global__ __launch_bounds__(256) void k_la_rows(
    const float* __restrict__ ent, const float* __restrict__ g, const float* __restrict__ b,
    const float* __restrict__ W, const float* __restrict__ wb,
    const float* __restrict__ w1s, const float* __restrict__ w2s, const float* __restrict__ cst,
    float* __restrict__ value, float* __restrict__ sum1, float* __restrict__ sum2, int n) {
  __shared__ float Wl[DIM * DIM];
  __shared__ float Ql[4][4][DIM];
  stageW(Wl, W);
  int lane = threadIdx.x & 63, wid = threadIdx.x >> 6;
  float* Qw = &Ql[wid][0][0];
  float2 gv  = *(const float2*)&g[2 * lane];
  float2 bv  = *(const float2*)&b[2 * lane];
  float2 wbv = *(const float2*)&wb[2 * lane];
  float2 w1v = *(const float2*)&w1s[2 * lane];
  float2 w2v = *(const float2*)&w2s[2 * lane];
  float b1s = cst[0], b2s = cst[1];
  int r0 = blockIdx.x * RPB;
#pragma unroll 1
  for (int p = 0; p < RPB / 16; ++p) {
    int rb = r0 + p * 16 + wid * 4;
#pragma unroll
    for (int j = 0; j < 4; ++j) {
      int r = rb + j;
      float2 x = (r < n) ? *(const float2*)&ent[(size_t)r * DIM + 2 * lane]
                         : make_float2(0.f, 0.f);
      float d0, d1;
      wave_ln(x.x, x.y, d0, d1);
      float q0 = fmaf(d0, gv.x, bv.x);
      float q1 = fmaf(d1, gv.y, bv.y);
      float p1 = wred(q0 * w1v.x + q1 * w1v.y);
      float p2 = wred(q0 * w2v.x + q1 * w2v.y);
      if (lane == 0 && r < n) { sum1[r] = tanhf(p1 + b1s); sum2[r] = tanhf(p2 + b2s); }
      *(float2*)&Qw[j * DIM + 2 * lane] = make_float2(q0, q1);
    }
    float2 acc[4];
    quad_gemv(Qw, Wl, lane, acc);
#pragma unroll
    for (int j = 0; j < 4; ++j) {
      int r = rb + j;
      if (r < n)
        *(float2*)&value[(size_t)r * DIM + 2 * lane] =
            make_float2(acc[j].x + wbv.x, acc[j].y + wbv.y);
    }
  }
}

// ---------- CSR build: histogram / scan / scatter ----------
__global__ __launch_bounds__(256) void k_hist(const int* __restrict__ src, int* __restrict__ cnt, int E) {
  int i = blockIdx.x * 256 + threadIdx.x, stride = gridDim.x * 256;
  for (; i < E; i += stride) atomicAdd(&cnt[src[i]], 1);
}

#define NSCAN 1024
__global__ __launch_bounds__(NSCAN) void k_scan(const int* __restrict__ cnt,
                                                int* __restrict__ starts,
                                                int* __restrict__ cursor, int n) {
  __shared__ int part[NSCAN];
  int t = threadIdx.x;
  int chunk = (n + NSCAN - 1) / NSCAN;
  int lo = t * chunk, hi = min(n, lo + chunk);
  int s = 0;
  for (int i = lo; i < hi; ++i) s += cnt[i];
  part[t] = s;
  __syncthreads();
  for (int off = 1; off < NSCAN; off <<= 1) {
    int other = (t >= off) ? part[t - off] : 0;
    __syncthreads();
    if (t >= off) part[t] += other;
    __syncthreads();
  }
  int run = (t == 0) ? 0 : part[t - 1];
  for (int i = lo; i < hi; ++i) {
    starts[i] = run; cursor[i] = run; run += cnt[i];
  }
}

__global__ __launch_bounds__(256) void k_scatter(const int* __restrict__ src, const int* __restrict__ dst,
                                                 int* __restrict__ cursor, int* __restrict__ sdst, int E) {
  int i = blockIdx.x * 256 + threadIdx.x, stride = gridDim.x * 256;
  for (; i < E; i += stride) {
    int pos = atomicAdd(&cursor[src[i]], 1);
    sdst[pos] = dst[i];
  }
}

// ---------- row accumulate: one wave per src row, no atomics ----------
__global__ __launch_bounds__(256) void k_accum(
    const int* __restrict__ starts, const int* __restrict__ ends,
    const int* __restrict__ sdst,
    const float* __restrict__ s1, const float* __restrict__ s2,
    const float* __restrict__ rows, float* __restrict__ outp, int n) {
  int lane = threadIdx.x & 63, wid = threadIdx.x >> 6;
  int r = blockIdx.x * 4 + wid;
  if (r >= n) return;
  int beg = starts[r], end = ends[r];
  float s1v = s1[r];
  float a0 = 0.f, a1 = 0.f, den = 0.f;
  int e = beg;
  int dNext = (e < end) ? sdst[e] : 0;
  while (e < end) {
    int d = dNext;
    ++e;
    dNext = (e < end) ? sdst[e] : 0;      // prefetch next index
    float s2v = s2[d];
    float2 v = *(const float2*)&rows[(size_t)d * DIM + 2 * lane];
    float x = s1v + s2v;
    x = x >= 0.f ? x : ALPHA * x;
    float w = __expf(x);                   // logits bounded in (-0.4, 2]: exact softmax
    a0 = fmaf(w, v.x, a0); a1 = fmaf(w, v.y, a1); den += w;
  }
  float inv = den > 0.f ? 1.f / den : 0.f;
  *(float2*)&outp[(size_t)r * DIM + 2 * lane] = make_float2(a0 * inv, a1 * inv);
}

// ---------- K3: local post: LN(ln2) in place -> e_out, er quadform sum1 ----------
__global__ __launch_bounds__(256) void k_la_post(
    float* __restrict__ buf,
    const float* __restrict__ g, const float* __restrict__ b,
    const float* __restrict__ W1, const float* __restrict__ w1b,
    float* __restrict__ sum1er, int n) {
  __shared__ float Wl[DIM * DIM];
  __shared__ float Ql[4][4][DIM];
  stageW(Wl, W1);
  int lane = threadIdx.x & 63, wid = threadIdx.x >> 6;
  float* Qw = &Ql[wid][0][0];
  float2 gv  = *(const float2*)&g[2 * lane];
  float2 bv  = *(const float2*)&b[2 * lane];
  float2 b1v = *(const float2*)&w1b[2 * lane];
  int r0 = blockIdx.x * RPB;
#pragma unroll 1
  for (int p = 0; p < RPB / 16; ++p) {
    int rb = r0 + p * 16 + wid * 4;
    float2 ev[4];
#pragma unroll
    for (int j = 0; j < 4; ++j) {
      int r = rb + j;
      float2 a = (r < n) ? *(const float2*)&buf[(size_t)r * DIM + 2 * lane]
                         : make_float2(0.f, 0.f);
      float d0, d1;
      wave_ln(a.x, a.y, d0, d1);
      ev[j].x = fmaf(d0, gv.x, bv.x);
      ev[j].y = fmaf(d1, gv.y, bv.y);
      if (r < n) *(float2*)&buf[(size_t)r * DIM + 2 * lane] = ev[j];
      *(float2*)&Qw[j * DIM + 2 * lane] = ev[j];
    }
    float2 acc[4];
    quad_gemv(Qw, Wl, lane, acc);
#pragma unroll
    for (int j = 0; j < 4; ++j) {
      int r = rb + j;
      float pq = wred(acc[j].x * ev[j].x + acc[j].y * ev[j].y +
                      b1v.x * ev[j].x + b1v.y * ev[j].y);
      if (lane == 0 && r < n) sum1er[r] = tanhf(pq);
    }
  }
}

// ---------- K4a: rel rows: LN(ea_ln1) -> dense GEMV (tiny, R=500) ----------
__global__ __launch_bounds__(256) void k_rel_dense(
    const float* __restrict__ rel, const float* __restrict__ g, const float* __restrict__ b,
    const float* __restrict__ W, const float* __restrict__ wb,
    float* __restrict__ dense, int n, int rowsPerBlock) {
  __shared__ float Wl[DIM * DIM];
  stageW(Wl, W);
  int lane = threadIdx.x & 63, wid = threadIdx.x >> 6;
  float2 gv  = *(const float2*)&g[2 * lane];
  float2 bv  = *(const float2*)&b[2 * lane];
  float2 wbv = *(const float2*)&wb[2 * lane];
  int r0 = blockIdx.x * rowsPerBlock, r1 = min(n, r0 + rowsPerBlock);
  for (int r = r0 + wid; r < r1; r += 4) {
    float2 x = *(const float2*)&rel[(size_t)r * DIM + 2 * lane];
    float d0, d1;
    wave_ln(x.x, x.y, d0, d1);
    float e0 = fmaf(d0, gv.x, bv.x);
    float e1 = fmaf(d1, gv.y, bv.y);
    float2 acc = wave_gemv(e0, e1, Wl, lane);
    acc.x += wbv.x; acc.y += wbv.y;
    *(float2*)&dense[(size_t)r * DIM + 2 * lane] = acc;
  }
}

// ---------- K4b: rel rows: LN(ea_ln1) -> quadform sum2_er (tiny) ----------
__global__ __launch_bounds__(256) void k_rel_quad(
    const float* __restrict__ rel, const float* __restrict__ g, const float* __restrict__ b,
    const float* __restrict__ W2, const float* __restrict__ w2b,
    float* __restrict__ sum2er, int n, int rowsPerBlock) {
  __shared__ float Wl[DIM * DIM];
  stageW(Wl, W2);
  int lane = threadIdx.x & 63, wid = threadIdx.x >> 6;
  float2 gv  = *(const float2*)&g[2 * lane];
  float2 bv  = *(const float2*)&b[2 * lane];
  float2 b2v = *(const float2*)&w2b[2 * lane];
  int r0 = blockIdx.x * rowsPerBlock, r1 = min(n, r0 + rowsPerBlock);
  for (int r = r0 + wid; r < r1; r += 4) {
    float2 x = *(const float2*)&rel[(size_t)r * DIM + 2 * lane];
    float d0, d1;
    wave_ln(x.x, x.y, d0, d1);
    float e0 = fmaf(d0, gv.x, bv.x);
    float e1 = fmaf(d1, gv.y, bv.y);
    float2 y = wave_gemv(e0, e1, Wl, lane);
    float p = wred(y.x * e0 + y.y * e1 + b2v.x * e0 + b2v.y * e1);
    if (lane == 0) sum2er[r] = tanhf(p);
  }
}

// ---------- K6: final: er LN, d1 GEMV, combine with e_out ----------
// acc2 aliases out (in-place safe: each thread reads its elements before writing them)
__global__ __launch_bounds__(256) void k_final(
    const float* acc2, const float* __restrict__ eout,
    const float* __restrict__ g, const float* __restrict__ b,
    const float* __restrict__ d1W, const float* __restrict__ d1b,
    float* out, int n) {
  __shared__ float Wl[DIM * DIM];
  __shared__ float Ql[4][4][DIM];
  stageW(Wl, d1W);
  int lane = threadIdx.x & 63, wid = threadIdx.x >> 6;
  float* Qw = &Ql[wid][0][0];
  float2 gv  = *(const float2*)&g[2 * lane];
  float2 bv  = *(const float2*)&b[2 * lane];
  float2 dbv = *(const float2*)&d1b[2 * lane];
  int r0 = blockIdx.x * RPB;
#pragma unroll 1
  for (int p = 0; p < RPB / 16; ++p) {
    int rb = r0 + p * 16 + wid * 4;
#pragma unroll
    for (int j = 0; j < 4; ++j) {
      int r = rb + j;
      float2 a = (r < n) ? *(const float2*)&acc2[(size_t)r * DIM + 2 * lane]
                         : make_float2(0.f, 0.f);
      float d0, d1;
      wave_ln(a.x, a.y, d0, d1);
      float er0 = fmaf(d0, gv.x, bv.x);
      float er1 = fmaf(d1, gv.y, bv.y);
      *(float2*)&Qw[j * DIM + 2 * lane] = make_float2(er0, er1);
    }
    float2 acc[4];
    quad_gemv(Qw, Wl, lane, acc);
#pragma unroll
    for (int j = 0; j < 4; ++j) {
      int r = rb + j;
      if (r < n) {
        float2 e = *(const float2*)&eout[(size_t)r * DIM + 2 * lane];
        float2 o;
        o.x = e.x + 0.6f * (acc[j].x + dbv.x);
        o.y = e.y + 0.6f * (acc[j].y + dbv.y);
        *(float2*)&out[(size_t)r * DIM + 2 * lane] = o;
      }
    }
  }
}

extern "C" void kernel_launch(void* const* d_in, const int* in_sizes, int n_in,
                              void* d_out, int out_size, void* d_ws, size_t ws_size,
                              hipStream_t stream) {
  const float* ent      = (const float*)d_in[0];
  const float* rel      = (const float*)d_in[1];
  const int*   esrc     = (const int*)d_in[2];
  const int*   edst     = (const int*)d_in[3];
  const int*   rsrc     = (const int*)d_in[4];
  const int*   rdst     = (const int*)d_in[5];
  const float* la_ln1_g = (const float*)d_in[6];
  const float* la_ln1_b = (const float*)d_in[7];
  const float* la_w_W   = (const float*)d_in[8];
  const float* la_w_b   = (const float*)d_in[9];
  const float* la_w1_W  = (const float*)d_in[10];
  const float* la_w1_b  = (const float*)d_in[11];
  const float* la_w2_W  = (const float*)d_in[12];
  const float* la_w2_b  = (const float*)d_in[13];
  const float* la_ln2_g = (const float*)d_in[14];
  const float* la_ln2_b = (const float*)d_in[15];
  const float* ea_ln1_g = (const float*)d_in[16];
  const float* ea_ln1_b = (const float*)d_in[17];
  const float* ea_w_W   = (const float*)d_in[18];
  const float* ea_w_b   = (const float*)d_in[19];
  const float* ea_w1_W  = (const float*)d_in[20];
  const float* ea_w1_b  = (const float*)d_in[21];
  const float* ea_w2_W  = (const float*)d_in[22];
  const float* ea_w2_b  = (const float*)d_in[23];
  const float* ea_ln2_g = (const float*)d_in[24];
  const float* ea_ln2_b = (const float*)d_in[25];
  const float* d1_W     = (const float*)d_in[26];
  const float* d1_b     = (const float*)d_in[27];
  float* out = (float*)d_out;

  // ws layout: ~16.67M slots (~66.7 MB)
  float* f      = (float*)d_ws;
  float* bufA   = f;                        // local numerator -> e_out (after LN)
  int*   sdst   = (int*)(f + 12800000);     // [E] sorted dst (reused for er)
  int*   cnt    = (int*)(f + 16000000);     // [N]
  int*   starts = (int*)(f + 16100000);     // [N]
  int*   cursor = (int*)(f + 16200000);     // [N] (becomes row-ends after scatter)
  float* sum1la = f + 16300000;             // [N]
  float* sum2la = f + 16400000;             // [N]
  float* sum1er = f + 16500000;             // [N]
  float* sum2er = f + 16600000;             // [R]
  float* dense  = f + 16600512;             // [R*128]
  float* w1s    = f + 16664512;             // [128]
  float* w2s    = f + 16664640;             // [128]
  float* cst    = f + 16664768;             // [2]
  float* value  = out;                      // [N*128] value lives in d_out during local phase

  const int gridRow = (N_ENT + RPB - 1) / RPB;   // 1563
  const int gridR   = 1;                          // 500 rows, rowsPerBlock=512
  const int gridA   = (N_ENT + 3) / 4;

  k_colsum<<<1, 128, 0, stream>>>(la_w1_W, la_w1_b, la_w2_W, la_w2_b, w1s, w2s, cst);
  k_la_rows<<<gridRow, 256, 0, stream>>>(ent, la_ln1_g, la_ln1_b, la_w_W, la_w_b,
                                         w1s, w2s, cst, value, sum1la, sum2la, N_ENT);

  // ---- local phase CSR + accumulate (no atomics on the 51MB accumulator) ----
  hipMemsetAsync(cnt, 0, N_ENT * sizeof(int), stream);
  k_hist<<<2048, 256, 0, stream>>>(esrc, cnt, N_EDGE);
  k_scan<<<1, NSCAN, 0, stream>>>(cnt, starts, cursor, N_ENT);
  k_scatter<<<2048, 256, 0, stream>>>(esrc, edst, cursor, sdst, N_EDGE);
  k_accum<<<gridA, 256, 0, stream>>>(starts, cursor, sdst, sum1la, sum2la,
                                     value, bufA, N_ENT);
  k_la_post<<<gridRow, 256, 0, stream>>>(bufA, la_ln2_g, la_ln2_b,
                                         ea_w1_W, ea_w1_b, sum1er, N_ENT);

  // ---- er phase ----
  k_rel_dense<<<gridR, 256, 0, stream>>>(rel, ea_ln1_g, ea_ln1_b, ea_w_W, ea_w_b,
                                         dense, N_REL, 512);
  k_rel_quad<<<gridR, 256, 0, stream>>>(rel, ea_ln1_g, ea_ln1_b, ea_w2_W, ea_w2_b,
                                        sum2er, N_REL, 512);
  hipMemsetAsync(cnt, 0, N_ENT * sizeof(int), stream);
  k_hist<<<2048, 256, 0, stream>>>(rsrc, cnt, N_EDGE);
  k_scan<<<1, NSCAN, 0, stream>>>(cnt, starts, cursor, N_ENT);
  k_scatter<<<2048, 256, 0, stream>>>(rsrc, rdst, cursor, sdst, N_EDGE);
  k_accum<<<gridA, 256, 0, stream>>>(starts, cursor, sdst, sum1er, sum2er,
                                     dense, out, N_ENT);   // er numerator -> d_out (value dead)

  k_final<<<gridRow, 256, 0, stream>>>(out, bufA, ea_ln2_g, ea_ln2_b,
                                       d1_W, d1_b, out, N_ENT);
}

// Round 7
// 3597.392 us; speedup vs baseline: 1.4638x; 1.4638x over previous
//
#include <hip/hip_runtime.h>
#include <math.h>

#define DIM 128
#define N_ENT 100000
#define N_REL 500
#define N_EDGE 3200000
#define LN_EPS 1e-6f
#define ALPHA 0.2f
#define RPB 64   // rows per block in row-kernels (4 waves x 4 rows x 4 passes)

// ---------- helpers ----------

__device__ __forceinline__ float wred(float v) {
#pragma unroll
  for (int o = 32; o > 0; o >>= 1) v += __shfl_xor(v, o, 64);
  return v;
}

// legacy one-row wave GEMV (used only for the tiny R=500 kernels)
__device__ __forceinline__ float2 wave_gemv(float q0, float q1, const float* __restrict__ Wl, int lane) {
  float ax = 0.f, ay = 0.f;
#pragma unroll
  for (int kk = 0; kk < 64; ++kk) {
    float qa = __shfl(q0, kk, 64);
    float qb = __shfl(q1, kk, 64);
    float2 w0 = *(const float2*)&Wl[(2 * kk) * DIM + 2 * lane];
    float2 w1 = *(const float2*)&Wl[(2 * kk + 1) * DIM + 2 * lane];
    ax = fmaf(qa, w0.x, ax); ay = fmaf(qa, w0.y, ay);
    ax = fmaf(qb, w1.x, ax); ay = fmaf(qb, w1.y, ay);
  }
  return make_float2(ax, ay);
}

__device__ __forceinline__ void stageW(float* Wl, const float* __restrict__ W) {
  for (int i = threadIdx.x; i < DIM * DIM / 4; i += blockDim.x)
    ((float4*)Wl)[i] = ((const float4*)W)[i];
  __syncthreads();
}

__device__ __forceinline__ void wave_ln(float x0, float x1, float& d0s, float& d1s) {
  float m = wred(x0 + x1) * (1.f / DIM);
  float d0 = x0 - m, d1 = x1 - m;
  float var = wred(d0 * d0 + d1 * d1) * (1.f / DIM);
  float rs = rsqrtf(var + LN_EPS);
  d0s = d0 * rs; d1s = d1 * rs;
}

// 4-rows-per-wave GEMV from per-wave q tile (broadcast reads) x W in LDS.
// acc[j] = q_row_j @ W, lane owns cols (2*lane, 2*lane+1).
// NOTE: unroll capped at 4 — full unroll (32 bodies) blew the register file
// (VGPR=256 + ~1.3GB spill traffic, round-6 profile).
__device__ __forceinline__ void quad_gemv(const float* __restrict__ Qw /*4x DIM*/,
                                          const float* __restrict__ Wl,
                                          int lane, float2 acc[4]) {
#pragma unroll
  for (int j = 0; j < 4; ++j) acc[j] = make_float2(0.f, 0.f);
#pragma unroll 4
  for (int k = 0; k < DIM; k += 4) {
    float4 qa = *(const float4*)&Qw[0 * DIM + k];
    float4 qb = *(const float4*)&Qw[1 * DIM + k];
    float4 qc = *(const float4*)&Qw[2 * DIM + k];
    float4 qd = *(const float4*)&Qw[3 * DIM + k];
    float2 w0 = *(const float2*)&Wl[(k + 0) * DIM + 2 * lane];
    float2 w1 = *(const float2*)&Wl[(k + 1) * DIM + 2 * lane];
    float2 w2 = *(const float2*)&Wl[(k + 2) * DIM + 2 * lane];
    float2 w3 = *(const float2*)&Wl[(k + 3) * DIM + 2 * lane];
    acc[0].x = fmaf(qa.x, w0.x, acc[0].x); acc[0].y = fmaf(qa.x, w0.y, acc[0].y);
    acc[0].x = fmaf(qa.y, w1.x, acc[0].x); acc[0].y = fmaf(qa.y, w1.y, acc[0].y);
    acc[0].x = fmaf(qa.z, w2.x, acc[0].x); acc[0].y = fmaf(qa.z, w2.y, acc[0].y);
    acc[0].x = fmaf(qa.w, w3.x, acc[0].x); acc[0].y = fmaf(qa.w, w3.y, acc[0].y);
    acc[1].x = fmaf(qb.x, w0.x, acc[1].x); acc[1].y = fmaf(qb.x, w0.y, acc[1].y);
    acc[1].x = fmaf(qb.y, w1.x, acc[1].x); acc[1].y = fmaf(qb.y, w1.y, acc[1].y);
    acc[1].x = fmaf(qb.z, w2.x, acc[1].x); acc[1].y = fmaf(qb.z, w2.y, acc[1].y);
    acc[1].x = fmaf(qb.w, w3.x, acc[1].x); acc[1].y = fmaf(qb.w, w3.y, acc[1].y);
    acc[2].x = fmaf(qc.x, w0.x, acc[2].x); acc[2].y = fmaf(qc.x, w0.y, acc[2].y);
    acc[2].x = fmaf(qc.y, w1.x, acc[2].x); acc[2].y = fmaf(qc.y, w1.y, acc[2].y);
    acc[2].x = fmaf(qc.z, w2.x, acc[2].x); acc[2].y = fmaf(qc.z, w2.y, acc[2].y);
    acc[2].x = fmaf(qc.w, w3.x, acc[2].x); acc[2].y = fmaf(qc.w, w3.y, acc[2].y);
    acc[3].x = fmaf(qd.x, w0.x, acc[3].x); acc[3].y = fmaf(qd.x, w0.y, acc[3].y);
    acc[3].x = fmaf(qd.y, w1.x, acc[3].x); acc[3].y = fmaf(qd.y, w1.y, acc[3].y);
    acc[3].x = fmaf(qd.z, w2.x, acc[3].x); acc[3].y = fmaf(qd.z, w2.y, acc[3].y);
    acc[3].x = fmaf(qd.w, w3.x, acc[3].x); acc[3].y = fmaf(qd.w, w3.y, acc[3].y);
  }
}

// ---------- precompute: column-structure sums for local-attn sum1/sum2 ----------
// sum(q@W1+b1, axis=1) == q . rowsum_j(W1[k][j]) + sum(b1)
__global__ void k_colsum(const float* __restrict__ W1, const float* __restrict__ b1,
                         const float* __restrict__ W2, const float* __restrict__ b2,
                         float* __restrict__ w1s, float* __restrict__ w2s, float* __restrict__ cst) {
  int t = threadIdx.x;  // 128 threads
  float s1 = 0.f, s2 = 0.f;
  for (int j = 0; j < DIM; ++j) { s1 += W1[t * DIM + j]; s2 += W2[t * DIM + j]; }
  w1s[t] = s1; w2s[t] = s2;
  if (t == 0) {
    float a = 0.f, c = 0.f;
    for (int j = 0; j < DIM; ++j) { a += b1[j]; c += b2[j]; }
    cst[0] = a; cst[1] = c;
  }
}

// ---------- K1: local-attn row pass: LN -> value GEMV, sum1/sum2 dots ----------
__global__ __launch_bounds__(256) void k_la_rows(
    const float* __restrict__ ent, const float* __restrict__ g, const float* __restrict__ b,
    const float* __restrict__ W, const float* __restrict__ wb,
    const float* __restrict__ w1s, const float* __restrict__ w2s, const float* __restrict__ cst,
    float* __restrict__ value, float* __restrict__ sum1, float* __restrict__ sum2, int n) {
  __shared__ float Wl[DIM * DIM];
  __shared__ float Ql[4][4][DIM];
  stageW(Wl, W);
  int lane = threadIdx.x & 63, wid = threadIdx.x >> 6;
  float* Qw = &Ql[wid][0][0];
  float2 gv  = *(const float2*)&g[2 * lane];
  float2 bv  = *(const float2*)&b[2 * lane];
  float2 wbv = *(const float2*)&wb[2 * lane];
  float2 w1v = *(const float2*)&w1s[2 * lane];
  float2 w2v = *(const float2*)&w2s[2 * lane];
  float b1s = cst[0], b2s = cst[1];
  int r0 = blockIdx.x * RPB;
#pragma unroll 1
  for (int p = 0; p < RPB / 16; ++p) {
    int rb = r0 + p * 16 + wid * 4;
#pragma unroll
    for (int j = 0; j < 4; ++j) {
      int r = rb + j;
      float2 x = (r < n) ? *(const float2*)&ent[(size_t)r * DIM + 2 * lane]
                         : make_float2(0.f, 0.f);
      float d0, d1;
      wave_ln(x.x, x.y, d0, d1);
      float q0 = fmaf(d0, gv.x, bv.x);
      float q1 = fmaf(d1, gv.y, bv.y);
      float p1 = wred(q0 * w1v.x + q1 * w1v.y);
      float p2 = wred(q0 * w2v.x + q1 * w2v.y);
      if (lane == 0 && r < n) { sum1[r] = tanhf(p1 + b1s); sum2[r] = tanhf(p2 + b2s); }
      *(float2*)&Qw[j * DIM + 2 * lane] = make_float2(q0, q1);
    }
    float2 acc[4];
    quad_gemv(Qw, Wl, lane, acc);
#pragma unroll
    for (int j = 0; j < 4; ++j) {
      int r = rb + j;
      if (r < n)
        *(float2*)&value[(size_t)r * DIM + 2 * lane] =
            make_float2(acc[j].x + wbv.x, acc[j].y + wbv.y);
    }
  }
}

// ---------- CSR build: histogram / scan / scatter ----------
__global__ __launch_bounds__(256) void k_hist(const int* __restrict__ src, int* __restrict__ cnt, int E) {
  int i = blockIdx.x * 256 + threadIdx.x, stride = gridDim.x * 256;
  for (; i < E; i += stride) atomicAdd(&cnt[src[i]], 1);
}

#define NSCAN 1024
__global__ __launch_bounds__(NSCAN) void k_scan(const int* __restrict__ cnt,
                                                int* __restrict__ starts,
                                                int* __restrict__ cursor, int n) {
  __shared__ int part[NSCAN];
  int t = threadIdx.x;
  int chunk = (n + NSCAN - 1) / NSCAN;
  int lo = t * chunk, hi = min(n, lo + chunk);
  int s = 0;
  for (int i = lo; i < hi; ++i) s += cnt[i];
  part[t] = s;
  __syncthreads();
  for (int off = 1; off < NSCAN; off <<= 1) {
    int other = (t >= off) ? part[t - off] : 0;
    __syncthreads();
    if (t >= off) part[t] += other;
    __syncthreads();
  }
  int run = (t == 0) ? 0 : part[t - 1];
  for (int i = lo; i < hi; ++i) {
    starts[i] = run; cursor[i] = run; run += cnt[i];
  }
}

__global__ __launch_bounds__(256) void k_scatter(const int* __restrict__ src, const int* __restrict__ dst,
                                                 int* __restrict__ cursor, int* __restrict__ sdst, int E) {
  int i = blockIdx.x * 256 + threadIdx.x, stride = gridDim.x * 256;
  for (; i < E; i += stride) {
    int pos = atomicAdd(&cursor[src[i]], 1);
    sdst[pos] = dst[i];
  }
}

// ---------- row accumulate: one wave per src row, no atomics ----------
__global__ __launch_bounds__(256) void k_accum(
    const int* __restrict__ starts, const int* __restrict__ ends,
    const int* __restrict__ sdst,
    const float* __restrict__ s1, const float* __restrict__ s2,
    const float* __restrict__ rows, float* __restrict__ outp, int n) {
  int lane = threadIdx.x & 63, wid = threadIdx.x >> 6;
  int r = blockIdx.x * 4 + wid;
  if (r >= n) return;
  int beg = starts[r], end = ends[r];
  float s1v = s1[r];
  float a0 = 0.f, a1 = 0.f, den = 0.f;
  int e = beg;
  int dNext = (e < end) ? sdst[e] : 0;
  while (e < end) {
    int d = dNext;
    ++e;
    dNext = (e < end) ? sdst[e] : 0;      // prefetch next index
    float s2v = s2[d];
    float2 v = *(const float2*)&rows[(size_t)d * DIM + 2 * lane];
    float x = s1v + s2v;
    x = x >= 0.f ? x : ALPHA * x;
    float w = __expf(x);                   // logits bounded in (-0.4, 2]: exact softmax
    a0 = fmaf(w, v.x, a0); a1 = fmaf(w, v.y, a1); den += w;
  }
  float inv = den > 0.f ? 1.f / den : 0.f;
  *(float2*)&outp[(size_t)r * DIM + 2 * lane] = make_float2(a0 * inv, a1 * inv);
}

// ---------- K3: local post: LN(ln2) in place -> e_out, er quadform sum1 ----------
__global__ __launch_bounds__(256) void k_la_post(
    float* __restrict__ buf,
    const float* __restrict__ g, const float* __restrict__ b,
    const float* __restrict__ W1, const float* __restrict__ w1b,
    float* __restrict__ sum1er, int n) {
  __shared__ float Wl[DIM * DIM];
  __shared__ float Ql[4][4][DIM];
  stageW(Wl, W1);
  int lane = threadIdx.x & 63, wid = threadIdx.x >> 6;
  float* Qw = &Ql[wid][0][0];
  float2 gv  = *(const float2*)&g[2 * lane];
  float2 bv  = *(const float2*)&b[2 * lane];
  float2 b1v = *(const float2*)&w1b[2 * lane];
  int r0 = blockIdx.x * RPB;
#pragma unroll 1
  for (int p = 0; p < RPB / 16; ++p) {
    int rb = r0 + p * 16 + wid * 4;
    float2 ev[4];
#pragma unroll
    for (int j = 0; j < 4; ++j) {
      int r = rb + j;
      float2 a = (r < n) ? *(const float2*)&buf[(size_t)r * DIM + 2 * lane]
                         : make_float2(0.f, 0.f);
      float d0, d1;
      wave_ln(a.x, a.y, d0, d1);
      ev[j].x = fmaf(d0, gv.x, bv.x);
      ev[j].y = fmaf(d1, gv.y, bv.y);
      if (r < n) *(float2*)&buf[(size_t)r * DIM + 2 * lane] = ev[j];
      *(float2*)&Qw[j * DIM + 2 * lane] = ev[j];
    }
    float2 acc[4];
    quad_gemv(Qw, Wl, lane, acc);
#pragma unroll
    for (int j = 0; j < 4; ++j) {
      int r = rb + j;
      float pq = wred(acc[j].x * ev[j].x + acc[j].y * ev[j].y +
                      b1v.x * ev[j].x + b1v.y * ev[j].y);
      if (lane == 0 && r < n) sum1er[r] = tanhf(pq);
    }
  }
}

// ---------- K4a: rel rows: LN(ea_ln1) -> dense GEMV (tiny, R=500) ----------
__global__ __launch_bounds__(256) void k_rel_dense(
    const float* __restrict__ rel, const float* __restrict__ g, const float* __restrict__ b,
    const float* __restrict__ W, const float* __restrict__ wb,
    float* __restrict__ dense, int n, int rowsPerBlock) {
  __shared__ float Wl[DIM * DIM];
  stageW(Wl, W);
  int lane = threadIdx.x & 63, wid = threadIdx.x >> 6;
  float2 gv  = *(const float2*)&g[2 * lane];
  float2 bv  = *(const float2*)&b[2 * lane];
  float2 wbv = *(const float2*)&wb[2 * lane];
  int r0 = blockIdx.x * rowsPerBlock, r1 = min(n, r0 + rowsPerBlock);
  for (int r = r0 + wid; r < r1; r += 4) {
    float2 x = *(const float2*)&rel[(size_t)r * DIM + 2 * lane];
    float d0, d1;
    wave_ln(x.x, x.y, d0, d1);
    float e0 = fmaf(d0, gv.x, bv.x);
    float e1 = fmaf(d1, gv.y, bv.y);
    float2 acc = wave_gemv(e0, e1, Wl, lane);
    acc.x += wbv.x; acc.y += wbv.y;
    *(float2*)&dense[(size_t)r * DIM + 2 * lane] = acc;
  }
}

// ---------- K4b: rel rows: LN(ea_ln1) -> quadform sum2_er (tiny) ----------
__global__ __launch_bounds__(256) void k_rel_quad(
    const float* __restrict__ rel, const float* __restrict__ g, const float* __restrict__ b,
    const float* __restrict__ W2, const float* __restrict__ w2b,
    float* __restrict__ sum2er, int n, int rowsPerBlock) {
  __shared__ float Wl[DIM * DIM];
  stageW(Wl, W2);
  int lane = threadIdx.x & 63, wid = threadIdx.x >> 6;
  float2 gv  = *(const float2*)&g[2 * lane];
  float2 bv  = *(const float2*)&b[2 * lane];
  float2 b2v = *(const float2*)&w2b[2 * lane];
  int r0 = blockIdx.x * rowsPerBlock, r1 = min(n, r0 + rowsPerBlock);
  for (int r = r0 + wid; r < r1; r += 4) {
    float2 x = *(const float2*)&rel[(size_t)r * DIM + 2 * lane];
    float d0, d1;
    wave_ln(x.x, x.y, d0, d1);
    float e0 = fmaf(d0, gv.x, bv.x);
    float e1 = fmaf(d1, gv.y, bv.y);
    float2 y = wave_gemv(e0, e1, Wl, lane);
    float p = wred(y.x * e0 + y.y * e1 + b2v.x * e0 + b2v.y * e1);
    if (lane == 0) sum2er[r] = tanhf(p);
  }
}

// ---------- K6: final: er LN, d1 GEMV, combine with e_out ----------
// acc2 aliases out (in-place safe: each thread reads its elements before writing them)
__global__ __launch_bounds__(256) void k_final(
    const float* acc2, const float* __restrict__ eout,
    const float* __restrict__ g, const float* __restrict__ b,
    const float* __restrict__ d1W, const float* __restrict__ d1b,
    float* out, int n) {
  __shared__ float Wl[DIM * DIM];
  __shared__ float Ql[4][4][DIM];
  stageW(Wl, d1W);
  int lane = threadIdx.x & 63, wid = threadIdx.x >> 6;
  float* Qw = &Ql[wid][0][0];
  float2 gv  = *(const float2*)&g[2 * lane];
  float2 bv  = *(const float2*)&b[2 * lane];
  float2 dbv = *(const float2*)&d1b[2 * lane];
  int r0 = blockIdx.x * RPB;
#pragma unroll 1
  for (int p = 0; p < RPB / 16; ++p) {
    int rb = r0 + p * 16 + wid * 4;
#pragma unroll
    for (int j = 0; j < 4; ++j) {
      int r = rb + j;
      float2 a = (r < n) ? *(const float2*)&acc2[(size_t)r * DIM + 2 * lane]
                         : make_float2(0.f, 0.f);
      float d0, d1;
      wave_ln(a.x, a.y, d0, d1);
      float er0 = fmaf(d0, gv.x, bv.x);
      float er1 = fmaf(d1, gv.y, bv.y);
      *(float2*)&Qw[j * DIM + 2 * lane] = make_float2(er0, er1);
    }
    float2 acc[4];
    quad_gemv(Qw, Wl, lane, acc);
#pragma unroll
    for (int j = 0; j < 4; ++j) {
      int r = rb + j;
      if (r < n) {
        float2 e = *(const float2*)&eout[(size_t)r * DIM + 2 * lane];
        float2 o;
        o.x = e.x + 0.6f * (acc[j].x + dbv.x);
        o.y = e.y + 0.6f * (acc[j].y + dbv.y);
        *(float2*)&out[(size_t)r * DIM + 2 * lane] = o;
      }
    }
  }
}

extern "C" void kernel_launch(void* const* d_in, const int* in_sizes, int n_in,
                              void* d_out, int out_size, void* d_ws, size_t ws_size,
                              hipStream_t stream) {
  const float* ent      = (const float*)d_in[0];
  const float* rel      = (const float*)d_in[1];
  const int*   esrc     = (const int*)d_in[2];
  const int*   edst     = (const int*)d_in[3];
  const int*   rsrc     = (const int*)d_in[4];
  const int*   rdst     = (const int*)d_in[5];
  const float* la_ln1_g = (const float*)d_in[6];
  const float* la_ln1_b = (const float*)d_in[7];
  const float* la_w_W   = (const float*)d_in[8];
  const float* la_w_b   = (const float*)d_in[9];
  const float* la_w1_W  = (const float*)d_in[10];
  const float* la_w1_b  = (const float*)d_in[11];
  const float* la_w2_W  = (const float*)d_in[12];
  const float* la_w2_b  = (const float*)d_in[13];
  const float* la_ln2_g = (const float*)d_in[14];
  const float* la_ln2_b = (const float*)d_in[15];
  const float* ea_ln1_g = (const float*)d_in[16];
  const float* ea_ln1_b = (const float*)d_in[17];
  const float* ea_w_W   = (const float*)d_in[18];
  const float* ea_w_b   = (const float*)d_in[19];
  const float* ea_w1_W  = (const float*)d_in[20];
  const float* ea_w1_b  = (const float*)d_in[21];
  const float* ea_w2_W  = (const float*)d_in[22];
  const float* ea_w2_b  = (const float*)d_in[23];
  const float* ea_ln2_g = (const float*)d_in[24];
  const float* ea_ln2_b = (const float*)d_in[25];
  const float* d1_W     = (const float*)d_in[26];
  const float* d1_b     = (const float*)d_in[27];
  float* out = (float*)d_out;

  // ws layout: ~16.67M slots (~66.7 MB)
  float* f      = (float*)d_ws;
  float* bufA   = f;                        // local numerator -> e_out (after LN)
  int*   sdst   = (int*)(f + 12800000);     // [E] sorted dst (reused for er)
  int*   cnt    = (int*)(f + 16000000);     // [N]
  int*   starts = (int*)(f + 16100000);     // [N]
  int*   cursor = (int*)(f + 16200000);     // [N] (becomes row-ends after scatter)
  float* sum1la = f + 16300000;             // [N]
  float* sum2la = f + 16400000;             // [N]
  float* sum1er = f + 16500000;             // [N]
  float* sum2er = f + 16600000;             // [R]
  float* dense  = f + 16600512;             // [R*128]
  float* w1s    = f + 16664512;             // [128]
  float* w2s    = f + 16664640;             // [128]
  float* cst    = f + 16664768;             // [2]
  float* value  = out;                      // [N*128] value lives in d_out during local phase

  const int gridRow = (N_ENT + RPB - 1) / RPB;   // 1563
  const int gridR   = 1;                          // 500 rows, rowsPerBlock=512
  const int gridA   = (N_ENT + 3) / 4;

  k_colsum<<<1, 128, 0, stream>>>(la_w1_W, la_w1_b, la_w2_W, la_w2_b, w1s, w2s, cst);
  k_la_rows<<<gridRow, 256, 0, stream>>>(ent, la_ln1_g, la_ln1_b, la_w_W, la_w_b,
                                         w1s, w2s, cst, value, sum1la, sum2la, N_ENT);

  // ---- local phase CSR + accumulate (no atomics on the 51MB accumulator) ----
  hipMemsetAsync(cnt, 0, N_ENT * sizeof(int), stream);
  k_hist<<<2048, 256, 0, stream>>>(esrc, cnt, N_EDGE);
  k_scan<<<1, NSCAN, 0, stream>>>(cnt, starts, cursor, N_ENT);
  k_scatter<<<2048, 256, 0, stream>>>(esrc, edst, cursor, sdst, N_EDGE);
  k_accum<<<gridA, 256, 0, stream>>>(starts, cursor, sdst, sum1la, sum2la,
                                     value, bufA, N_ENT);
  k_la_post<<<gridRow, 256, 0, stream>>>(bufA, la_ln2_g, la_ln2_b,
                                         ea_w1_W, ea_w1_b, sum1er, N_ENT);

  // ---- er phase ----
  k_rel_dense<<<gridR, 256, 0, stream>>>(rel, ea_ln1_g, ea_ln1_b, ea_w_W, ea_w_b,
                                         dense, N_REL, 512);
  k_rel_quad<<<gridR, 256, 0, stream>>>(rel, ea_ln1_g, ea_ln1_b, ea_w2_W, ea_w2_b,
                                        sum2er, N_REL, 512);
  hipMemsetAsync(cnt, 0, N_ENT * sizeof(int), stream);
  k_hist<<<2048, 256, 0, stream>>>(rsrc, cnt, N_EDGE);
  k_scan<<<1, NSCAN, 0, stream>>>(cnt, starts, cursor, N_ENT);
  k_scatter<<<2048, 256, 0, stream>>>(rsrc, rdst, cursor, sdst, N_EDGE);
  k_accum<<<gridA, 256, 0, stream>>>(starts, cursor, sdst, sum1er, sum2er,
                                     dense, out, N_ENT);   // er numerator -> d_out (value dead)

  k_final<<<gridRow, 256, 0, stream>>>(out, bufA, ea_ln2_g, ea_ln2_b,
                                       d1_W, d1_b, out, N_ENT);
}

// Round 10
// 2392.739 us; speedup vs baseline: 2.2007x; 1.5035x over previous
//
#include <hip/hip_runtime.h>
#include <math.h>

#define DIM 128
#define N_ENT 100000
#define N_REL 500
#define N_EDGE 3200000
#define LN_EPS 1e-6f
#define ALPHA 0.2f
#define RPB 64   // rows per block in row-kernels (4 waves x 4 rows x 4 passes)

// ---------- helpers ----------

__device__ __forceinline__ float wred(float v) {
#pragma unroll
  for (int o = 32; o > 0; o >>= 1) v += __shfl_xor(v, o, 64);
  return v;
}

// legacy one-row wave GEMV (used only for the tiny R=500 kernels)
__device__ __forceinline__ float2 wave_gemv(float q0, float q1, const float* __restrict__ Wl, int lane) {
  float ax = 0.f, ay = 0.f;
#pragma unroll
  for (int kk = 0; kk < 64; ++kk) {
    float qa = __shfl(q0, kk, 64);
    float qb = __shfl(q1, kk, 64);
    float2 w0 = *(const float2*)&Wl[(2 * kk) * DIM + 2 * lane];
    float2 w1 = *(const float2*)&Wl[(2 * kk + 1) * DIM + 2 * lane];
    ax = fmaf(qa, w0.x, ax); ay = fmaf(qa, w0.y, ay);
    ax = fmaf(qb, w1.x, ax); ay = fmaf(qb, w1.y, ay);
  }
  return make_float2(ax, ay);
}

__device__ __forceinline__ void stageW(float* Wl, const float* __restrict__ W) {
  for (int i = threadIdx.x; i < DIM * DIM / 4; i += blockDim.x)
    ((float4*)Wl)[i] = ((const float4*)W)[i];
  __syncthreads();
}

__device__ __forceinline__ void wave_ln(float x0, float x1, float& d0s, float& d1s) {
  float m = wred(x0 + x1) * (1.f / DIM);
  float d0 = x0 - m, d1 = x1 - m;
  float var = wred(d0 * d0 + d1 * d1) * (1.f / DIM);
  float rs = rsqrtf(var + LN_EPS);
  d0s = d0 * rs; d1s = d1 * rs;
}

// 4-rows-per-wave GEMV from per-wave q tile (broadcast reads) x W in LDS.
// acc[j] = q_row_j @ W, lane owns cols (2*lane, 2*lane+1).
// NOTE: unroll capped at 4 — full unroll (32 bodies) blew the register file
// (VGPR=256 + ~1.3GB spill traffic, round-6 profile).
__device__ __forceinline__ void quad_gemv(const float* __restrict__ Qw /*4x DIM*/,
                                          const float* __restrict__ Wl,
                                          int lane, float2 acc[4]) {
#pragma unroll
  for (int j = 0; j < 4; ++j) acc[j] = make_float2(0.f, 0.f);
#pragma unroll 4
  for (int k = 0; k < DIM; k += 4) {
    float4 qa = *(const float4*)&Qw[0 * DIM + k];
    float4 qb = *(const float4*)&Qw[1 * DIM + k];
    float4 qc = *(const float4*)&Qw[2 * DIM + k];
    float4 qd = *(const float4*)&Qw[3 * DIM + k];
    float2 w0 = *(const float2*)&Wl[(k + 0) * DIM + 2 * lane];
    float2 w1 = *(const float2*)&Wl[(k + 1) * DIM + 2 * lane];
    float2 w2 = *(const float2*)&Wl[(k + 2) * DIM + 2 * lane];
    float2 w3 = *(const float2*)&Wl[(k + 3) * DIM + 2 * lane];
    acc[0].x = fmaf(qa.x, w0.x, acc[0].x); acc[0].y = fmaf(qa.x, w0.y, acc[0].y);
    acc[0].x = fmaf(qa.y, w1.x, acc[0].x); acc[0].y = fmaf(qa.y, w1.y, acc[0].y);
    acc[0].x = fmaf(qa.z, w2.x, acc[0].x); acc[0].y = fmaf(qa.z, w2.y, acc[0].y);
    acc[0].x = fmaf(qa.w, w3.x, acc[0].x); acc[0].y = fmaf(qa.w, w3.y, acc[0].y);
    acc[1].x = fmaf(qb.x, w0.x, acc[1].x); acc[1].y = fmaf(qb.x, w0.y, acc[1].y);
    acc[1].x = fmaf(qb.y, w1.x, acc[1].x); acc[1].y = fmaf(qb.y, w1.y, acc[1].y);
    acc[1].x = fmaf(qb.z, w2.x, acc[1].x); acc[1].y = fmaf(qb.z, w2.y, acc[1].y);
    acc[1].x = fmaf(qb.w, w3.x, acc[1].x); acc[1].y = fmaf(qb.w, w3.y, acc[1].y);
    acc[2].x = fmaf(qc.x, w0.x, acc[2].x); acc[2].y = fmaf(qc.x, w0.y, acc[2].y);
    acc[2].x = fmaf(qc.y, w1.x, acc[2].x); acc[2].y = fmaf(qc.y, w1.y, acc[2].y);
    acc[2].x = fmaf(qc.z, w2.x, acc[2].x); acc[2].y = fmaf(qc.z, w2.y, acc[2].y);
    acc[2].x = fmaf(qc.w, w3.x, acc[2].x); acc[2].y = fmaf(qc.w, w3.y, acc[2].y);
    acc[3].x = fmaf(qd.x, w0.x, acc[3].x); acc[3].y = fmaf(qd.x, w0.y, acc[3].y);
    acc[3].x = fmaf(qd.y, w1.x, acc[3].x); acc[3].y = fmaf(qd.y, w1.y, acc[3].y);
    acc[3].x = fmaf(qd.z, w2.x, acc[3].x); acc[3].y = fmaf(qd.z, w2.y, acc[3].y);
    acc[3].x = fmaf(qd.w, w3.x, acc[3].x); acc[3].y = fmaf(qd.w, w3.y, acc[3].y);
  }
}

// ---------- precompute: column-structure sums for local-attn sum1/sum2 ----------
// sum(q@W1+b1, axis=1) == q . rowsum_j(W1[k][j]) + sum(b1)
__global__ void k_colsum(const float* __restrict__ W1, const float* __restrict__ b1,
                         const float* __restrict__ W2, const float* __restrict__ b2,
                         float* __restrict__ w1s, float* __restrict__ w2s, float* __restrict__ cst) {
  int t = threadIdx.x;  // 128 threads
  float s1 = 0.f, s2 = 0.f;
  for (int j = 0; j < DIM; ++j) { s1 += W1[t * DIM + j]; s2 += W2[t * DIM + j]; }
  w1s[t] = s1; w2s[t] = s2;
  if (t == 0) {
    float a = 0.f, c = 0.f;
    for (int j = 0; j < DIM; ++j) { a += b1[j]; c += b2[j]; }
    cst[0] = a; cst[1] = c;
  }
}

// ---------- K1: local-attn row pass: LN -> value GEMV, sum1/sum2 dots ----------
__global__ __launch_bounds__(256) void k_la_rows(
    const float* __restrict__ ent, const float* __restrict__ g, const float* __restrict__ b,
    const float* __restrict__ W, const float* __restrict__ wb,
    const float* __restrict__ w1s, const float* __restrict__ w2s, const float* __restrict__ cst,
    float* __restrict__ value, float* __restrict__ sum1, float* __restrict__ sum2, int n) {
  __shared__ float Wl[DIM * DIM];
  __shared__ float Ql[4][4][DIM];
  stageW(Wl, W);
  int lane = threadIdx.x & 63, wid = threadIdx.x >> 6;
  float* Qw = &Ql[wid][0][0];
  float2 gv  = *(const float2*)&g[2 * lane];
  float2 bv  = *(const float2*)&b[2 * lane];
  float2 wbv = *(const float2*)&wb[2 * lane];
  float2 w1v = *(const float2*)&w1s[2 * lane];
  float2 w2v = *(const float2*)&w2s[2 * lane];
  float b1s = cst[0], b2s = cst[1];
  int r0 = blockIdx.x * RPB;
#pragma unroll 1
  for (int p = 0; p < RPB / 16; ++p) {
    int rb = r0 + p * 16 + wid * 4;
#pragma unroll
    for (int j = 0; j < 4; ++j) {
      int r = rb + j;
      float2 x = (r < n) ? *(const float2*)&ent[(size_t)r * DIM + 2 * lane]
                         : make_float2(0.f, 0.f);
      float d0, d1;
      wave_ln(x.x, x.y, d0, d1);
      float q0 = fmaf(d0, gv.x, bv.x);
      float q1 = fmaf(d1, gv.y, bv.y);
      float p1 = wred(q0 * w1v.x + q1 * w1v.y);
      float p2 = wred(q0 * w2v.x + q1 * w2v.y);
      if (lane == 0 && r < n) { sum1[r] = tanhf(p1 + b1s); sum2[r] = tanhf(p2 + b2s); }
      *(float2*)&Qw[j * DIM + 2 * lane] = make_float2(q0, q1);
    }
    float2 acc[4];
    quad_gemv(Qw, Wl, lane, acc);
#pragma unroll
    for (int j = 0; j < 4; ++j) {
      int r = rb + j;
      if (r < n)
        *(float2*)&value[(size_t)r * DIM + 2 * lane] =
            make_float2(acc[j].x + wbv.x, acc[j].y + wbv.y);
    }
  }
}

// ---------- CSR build: histogram / scan / scatter ----------
__global__ __launch_bounds__(256) void k_hist(const int* __restrict__ src, int* __restrict__ cnt, int E) {
  int i = blockIdx.x * 256 + threadIdx.x, stride = gridDim.x * 256;
  for (; i < E; i += stride) atomicAdd(&cnt[src[i]], 1);
}

#define NSCAN 1024
__global__ __launch_bounds__(NSCAN) void k_scan(const int* __restrict__ cnt,
                                                int* __restrict__ starts,
                                                int* __restrict__ cursor, int n) {
  __shared__ int part[NSCAN];
  int t = threadIdx.x;
  int chunk = (n + NSCAN - 1) / NSCAN;
  int lo = t * chunk, hi = min(n, lo + chunk);
  int s = 0;
  for (int i = lo; i < hi; ++i) s += cnt[i];
  part[t] = s;
  __syncthreads();
  for (int off = 1; off < NSCAN; off <<= 1) {
    int other = (t >= off) ? part[t - off] : 0;
    __syncthreads();
    if (t >= off) part[t] += other;
    __syncthreads();
  }
  int run = (t == 0) ? 0 : part[t - 1];
  for (int i = lo; i < hi; ++i) {
    starts[i] = run; cursor[i] = run; run += cnt[i];
  }
}

__global__ __launch_bounds__(256) void k_scatter(const int* __restrict__ src, const int* __restrict__ dst,
                                                 int* __restrict__ cursor, int* __restrict__ sdst, int E) {
  int i = blockIdx.x * 256 + threadIdx.x, stride = gridDim.x * 256;
  for (; i < E; i += stride) {
    int pos = atomicAdd(&cursor[src[i]], 1);
    sdst[pos] = dst[i];
  }
}

// ---------- row accumulate: one wave per src row, no atomics ----------
__global__ __launch_bounds__(256) void k_accum(
    const int* __restrict__ starts, const int* __restrict__ ends,
    const int* __restrict__ sdst,
    const float* __restrict__ s1, const float* __restrict__ s2,
    const float* __restrict__ rows, float* __restrict__ outp, int n) {
  int lane = threadIdx.x & 63, wid = threadIdx.x >> 6;
  int r = blockIdx.x * 4 + wid;
  if (r >= n) return;
  int beg = starts[r], end = ends[r];
  float s1v = s1[r];
  float a0 = 0.f, a1 = 0.f, den = 0.f;
  int e = beg;
  int dNext = (e < end) ? sdst[e] : 0;
  while (e < end) {
    int d = dNext;
    ++e;
    dNext = (e < end) ? sdst[e] : 0;      // prefetch next index
    float s2v = s2[d];
    float2 v = *(const float2*)&rows[(size_t)d * DIM + 2 * lane];
    float x = s1v + s2v;
    x = x >= 0.f ? x : ALPHA * x;
    float w = __expf(x);                   // logits bounded in (-0.4, 2]: exact softmax
    a0 = fmaf(w, v.x, a0); a1 = fmaf(w, v.y, a1); den += w;
  }
  float inv = den > 0.f ? 1.f / den : 0.f;
  *(float2*)&outp[(size_t)r * DIM + 2 * lane] = make_float2(a0 * inv, a1 * inv);
}

// ---------- K3: local post: LN(ln2) in place -> e_out, er quadform sum1 ----------
__global__ __launch_bounds__(256) void k_la_post(
    float* __restrict__ buf,
    const float* __restrict__ g, const float* __restrict__ b,
    const float* __restrict__ W1, const float* __restrict__ w1b,
    float* __restrict__ sum1er, int n) {
  __shared__ float Wl[DIM * DIM];
  __shared__ float Ql[4][4][DIM];
  stageW(Wl, W1);
  int lane = threadIdx.x & 63, wid = threadIdx.x >> 6;
  float* Qw = &Ql[wid][0][0];
  float2 gv  = *(const float2*)&g[2 * lane];
  float2 bv  = *(const float2*)&b[2 * lane];
  float2 b1v = *(const float2*)&w1b[2 * lane];
  int r0 = blockIdx.x * RPB;
#pragma unroll 1
  for (int p = 0; p < RPB / 16; ++p) {
    int rb = r0 + p * 16 + wid * 4;
    float2 ev[4];
#pragma unroll
    for (int j = 0; j < 4; ++j) {
      int r = rb + j;
      float2 a = (r < n) ? *(const float2*)&buf[(size_t)r * DIM + 2 * lane]
                         : make_float2(0.f, 0.f);
      float d0, d1;
      wave_ln(a.x, a.y, d0, d1);
      ev[j].x = fmaf(d0, gv.x, bv.x);
      ev[j].y = fmaf(d1, gv.y, bv.y);
      if (r < n) *(float2*)&buf[(size_t)r * DIM + 2 * lane] = ev[j];
      *(float2*)&Qw[j * DIM + 2 * lane] = ev[j];
    }
    float2 acc[4];
    quad_gemv(Qw, Wl, lane, acc);
#pragma unroll
    for (int j = 0; j < 4; ++j) {
      int r = rb + j;
      float pq = wred(acc[j].x * ev[j].x + acc[j].y * ev[j].y +
                      b1v.x * ev[j].x + b1v.y * ev[j].y);
      if (lane == 0 && r < n) sum1er[r] = tanhf(pq);
    }
  }
}

// ---------- K4a: rel rows: LN(ea_ln1) -> dense GEMV (R=500, one row/wave) ----------
__global__ __launch_bounds__(256) void k_rel_dense(
    const float* __restrict__ rel, const float* __restrict__ g, const float* __restrict__ b,
    const float* __restrict__ W, const float* __restrict__ wb,
    float* __restrict__ dense, int n) {
  __shared__ float Wl[DIM * DIM];
  stageW(Wl, W);
  int lane = threadIdx.x & 63, wid = threadIdx.x >> 6;
  int r = blockIdx.x * 4 + wid;
  if (r >= n) return;
  float2 gv  = *(const float2*)&g[2 * lane];
  float2 bv  = *(const float2*)&b[2 * lane];
  float2 wbv = *(const float2*)&wb[2 * lane];
  float2 x = *(const float2*)&rel[(size_t)r * DIM + 2 * lane];
  float d0, d1;
  wave_ln(x.x, x.y, d0, d1);
  float e0 = fmaf(d0, gv.x, bv.x);
  float e1 = fmaf(d1, gv.y, bv.y);
  float2 acc = wave_gemv(e0, e1, Wl, lane);
  acc.x += wbv.x; acc.y += wbv.y;
  *(float2*)&dense[(size_t)r * DIM + 2 * lane] = acc;
}

// ---------- K4b: rel rows: LN(ea_ln1) -> quadform sum2_er (R=500, one row/wave) ----------
__global__ __launch_bounds__(256) void k_rel_quad(
    const float* __restrict__ rel, const float* __restrict__ g, const float* __restrict__ b,
    const float* __restrict__ W2, const float* __restrict__ w2b,
    float* __restrict__ sum2er, int n) {
  __shared__ float Wl[DIM * DIM];
  stageW(Wl, W2);
  int lane = threadIdx.x & 63, wid = threadIdx.x >> 6;
  int r = blockIdx.x * 4 + wid;
  if (r >= n) return;
  float2 gv  = *(const float2*)&g[2 * lane];
  float2 bv  = *(const float2*)&b[2 * lane];
  float2 b2v = *(const float2*)&w2b[2 * lane];
  float2 x = *(const float2*)&rel[(size_t)r * DIM + 2 * lane];
  float d0, d1;
  wave_ln(x.x, x.y, d0, d1);
  float e0 = fmaf(d0, gv.x, bv.x);
  float e1 = fmaf(d1, gv.y, bv.y);
  float2 y = wave_gemv(e0, e1, Wl, lane);
  float p = wred(y.x * e0 + y.y * e1 + b2v.x * e0 + b2v.y * e1);
  if (lane == 0) sum2er[r] = tanhf(p);
}

// ---------- K6: final: er LN, d1 GEMV, combine with e_out ----------
// acc2 aliases out (in-place safe: each thread reads its elements before writing them)
__global__ __launch_bounds__(256) void k_final(
    const float* acc2, const float* __restrict__ eout,
    const float* __restrict__ g, const float* __restrict__ b,
    const float* __restrict__ d1W, const float* __restrict__ d1b,
    float* out, int n) {
  __shared__ float Wl[DIM * DIM];
  __shared__ float Ql[4][4][DIM];
  stageW(Wl, d1W);
  int lane = threadIdx.x & 63, wid = threadIdx.x >> 6;
  float* Qw = &Ql[wid][0][0];
  float2 gv  = *(const float2*)&g[2 * lane];
  float2 bv  = *(const float2*)&b[2 * lane];
  float2 dbv = *(const float2*)&d1b[2 * lane];
  int r0 = blockIdx.x * RPB;
#pragma unroll 1
  for (int p = 0; p < RPB / 16; ++p) {
    int rb = r0 + p * 16 + wid * 4;
#pragma unroll
    for (int j = 0; j < 4; ++j) {
      int r = rb + j;
      float2 a = (r < n) ? *(const float2*)&acc2[(size_t)r * DIM + 2 * lane]
                         : make_float2(0.f, 0.f);
      float d0, d1;
      wave_ln(a.x, a.y, d0, d1);
      float er0 = fmaf(d0, gv.x, bv.x);
      float er1 = fmaf(d1, gv.y, bv.y);
      *(float2*)&Qw[j * DIM + 2 * lane] = make_float2(er0, er1);
    }
    float2 acc[4];
    quad_gemv(Qw, Wl, lane, acc);
#pragma unroll
    for (int j = 0; j < 4; ++j) {
      int r = rb + j;
      if (r < n) {
        float2 e = *(const float2*)&eout[(size_t)r * DIM + 2 * lane];
        float2 o;
        o.x = e.x + 0.6f * (acc[j].x + dbv.x);
        o.y = e.y + 0.6f * (acc[j].y + dbv.y);
        *(float2*)&out[(size_t)r * DIM + 2 * lane] = o;
      }
    }
  }
}

extern "C" void kernel_launch(void* const* d_in, const int* in_sizes, int n_in,
                              void* d_out, int out_size, void* d_ws, size_t ws_size,
                              hipStream_t stream) {
  const float* ent      = (const float*)d_in[0];
  const float* rel      = (const float*)d_in[1];
  const int*   esrc     = (const int*)d_in[2];
  const int*   edst     = (const int*)d_in[3];
  const int*   rsrc     = (const int*)d_in[4];
  const int*   rdst     = (const int*)d_in[5];
  const float* la_ln1_g = (const float*)d_in[6];
  const float* la_ln1_b = (const float*)d_in[7];
  const float* la_w_W   = (const float*)d_in[8];
  const float* la_w_b   = (const float*)d_in[9];
  const float* la_w1_W  = (const float*)d_in[10];
  const float* la_w1_b  = (const float*)d_in[11];
  const float* la_w2_W  = (const float*)d_in[12];
  const float* la_w2_b  = (const float*)d_in[13];
  const float* la_ln2_g = (const float*)d_in[14];
  const float* la_ln2_b = (const float*)d_in[15];
  const float* ea_ln1_g = (const float*)d_in[16];
  const float* ea_ln1_b = (const float*)d_in[17];
  const float* ea_w_W   = (const float*)d_in[18];
  const float* ea_w_b   = (const float*)d_in[19];
  const float* ea_w1_W  = (const float*)d_in[20];
  const float* ea_w1_b  = (const float*)d_in[21];
  const float* ea_w2_W  = (const float*)d_in[22];
  const float* ea_w2_b  = (const float*)d_in[23];
  const float* ea_ln2_g = (const float*)d_in[24];
  const float* ea_ln2_b = (const float*)d_in[25];
  const float* d1_W     = (const float*)d_in[26];
  const float* d1_b     = (const float*)d_in[27];
  float* out = (float*)d_out;

  // ws layout: ~16.67M slots (~66.7 MB)
  float* f      = (float*)d_ws;
  float* bufA   = f;                        // local numerator -> e_out (after LN)
  int*   sdst   = (int*)(f + 12800000);     // [E] sorted dst (reused for er)
  int*   cnt    = (int*)(f + 16000000);     // [N]
  int*   starts = (int*)(f + 16100000);     // [N]
  int*   cursor = (int*)(f + 16200000);     // [N] (becomes row-ends after scatter)
  float* sum1la = f + 16300000;             // [N]
  float* sum2la = f + 16400000;             // [N]
  float* sum1er = f + 16500000;             // [N]
  float* sum2er = f + 16600000;             // [R]
  float* dense  = f + 16600512;             // [R*128]
  float* w1s    = f + 16664512;             // [128]
  float* w2s    = f + 16664640;             // [128]
  float* cst    = f + 16664768;             // [2]
  float* value  = out;                      // [N*128] value lives in d_out during local phase

  const int gridRow = (N_ENT + RPB - 1) / RPB;   // 1563
  const int gridR   = (N_REL + 3) / 4;            // 125 blocks, one row per wave
  const int gridA   = (N_ENT + 3) / 4;

  k_colsum<<<1, 128, 0, stream>>>(la_w1_W, la_w1_b, la_w2_W, la_w2_b, w1s, w2s, cst);
  k_la_rows<<<gridRow, 256, 0, stream>>>(ent, la_ln1_g, la_ln1_b, la_w_W, la_w_b,
                                         w1s, w2s, cst, value, sum1la, sum2la, N_ENT);

  // ---- local phase CSR + accumulate (no atomics on the 51MB accumulator) ----
  hipMemsetAsync(cnt, 0, N_ENT * sizeof(int), stream);
  k_hist<<<2048, 256, 0, stream>>>(esrc, cnt, N_EDGE);
  k_scan<<<1, NSCAN, 0, stream>>>(cnt, starts, cursor, N_ENT);
  k_scatter<<<2048, 256, 0, stream>>>(esrc, edst, cursor, sdst, N_EDGE);
  k_accum<<<gridA, 256, 0, stream>>>(starts, cursor, sdst, sum1la, sum2la,
                                     value, bufA, N_ENT);
  k_la_post<<<gridRow, 256, 0, stream>>>(bufA, la_ln2_g, la_ln2_b,
                                         ea_w1_W, ea_w1_b, sum1er, N_ENT);

  // ---- er phase ----
  k_rel_dense<<<gridR, 256, 0, stream>>>(rel, ea_ln1_g, ea_ln1_b, ea_w_W, ea_w_b,
                                         dense, N_REL);
  k_rel_quad<<<gridR, 256, 0, stream>>>(rel, ea_ln1_g, ea_ln1_b, ea_w2_W, ea_w2_b,
                                        sum2er, N_REL);
  hipMemsetAsync(cnt, 0, N_ENT * sizeof(int), stream);
  k_hist<<<2048, 256, 0, stream>>>(rsrc, cnt, N_EDGE);
  k_scan<<<1, NSCAN, 0, stream>>>(cnt, starts, cursor, N_ENT);
  k_scatter<<<2048, 256, 0, stream>>>(rsrc, rdst, cursor, sdst, N_EDGE);
  k_accum<<<gridA, 256, 0, stream>>>(starts, cursor, sdst, sum1er, sum2er,
                                     dense, out, N_ENT);   // er numerator -> d_out (value dead)

  k_final<<<gridRow, 256, 0, stream>>>(out, bufA, ea_ln2_g, ea_ln2_b,
                                       d1_W, d1_b, out, N_ENT);
}